// Round 6
// baseline (274.874 us; speedup 1.0000x reference)
//
#include <hip/hip_runtime.h>
#include <math.h>

#define BATCH 8
#define CH    256
#define NPIX  4096
#define CKDIM 64

typedef __attribute__((ext_vector_type(8))) short short8;   // 8 bf16 (4 VGPRs)
typedef __attribute__((ext_vector_type(4))) float f32x4;    // MFMA accumulator

#define MFMA16x16(a, b, c) __builtin_amdgcn_mfma_f32_16x16x32_bf16((a), (b), (c), 0, 0, 0)

__device__ __forceinline__ unsigned short f2bf(float f) {
    union { float f; unsigned int u; } v; v.f = f;
    unsigned int u = v.u;
    u += 0x7fffu + ((u >> 16) & 1u);      // round-to-nearest-even
    return (unsigned short)(u >> 16);
}

// ---------------------------------------------------------------------------
// Kernel P: build W_all[384][256] bf16 (rows 0-63 wq, 64-127 wk, 128-383 wg@wv)
// + bias_all[384] f32. 48 blocks x 256 thr, 8 rows/block; wg staged in LDS so
// wv is read coalesced once per block (8 MB L2 total, was 64 MB).
// ---------------------------------------------------------------------------
__global__ void prep_kernel(const float* __restrict__ wq, const float* __restrict__ bq,
                            const float* __restrict__ wk, const float* __restrict__ bk,
                            const float* __restrict__ wv, const float* __restrict__ bv,
                            const float* __restrict__ wg,
                            unsigned short* __restrict__ W_all, float* __restrict__ bias_all) {
    int bo  = blockIdx.x;      // 0..47
    int tid = threadIdx.x;     // 0..255
    if (bo < 16) {
        int r0 = bo * 8;
#pragma unroll
        for (int r = 0; r < 8; ++r) {
            int o = r0 + r;
            float v = (o < 64) ? wq[o * CH + tid] : wk[(o - 64) * CH + tid];
            W_all[o * CH + tid] = f2bf(v);
        }
        if (tid < 8) {
            int o = r0 + tid;
            bias_all[o] = (o < 64) ? bq[o] : bk[o - 64];
        }
    } else {
        int ob = (bo - 16) * 8;    // v' row block
        __shared__ float wgl[8][256];
#pragma unroll
        for (int r = 0; r < 8; ++r) wgl[r][tid] = wg[(size_t)(ob + r) * CH + tid];
        __syncthreads();
        float acc[8];
#pragma unroll
        for (int r = 0; r < 8; ++r) acc[r] = 0.f;
        for (int m = 0; m < CH; ++m) {
            float wvv = wv[(size_t)m * CH + tid];
#pragma unroll
            for (int r = 0; r < 8; ++r) acc[r] += wgl[r][m] * wvv;
        }
#pragma unroll
        for (int r = 0; r < 8; ++r)
            W_all[(size_t)(128 + ob + r) * CH + tid] = f2bf(acc[r]);
        if (tid < 8) {
            float bb = 0.f;
            for (int m = 0; m < CH; ++m) bb += wgl[tid][m] * bv[m];
            bias_all[128 + ob + tid] = bb;
        }
    }
}

// ---------------------------------------------------------------------------
// Kernel T: transpose+convert x[b][c][n] fp32 -> xt[b][n][c] bf16.
// ---------------------------------------------------------------------------
__global__ void xpose_kernel(const float* __restrict__ x, unsigned short* __restrict__ xt) {
    __shared__ float Tl[64][65];
    int n0 = blockIdx.x * 64;
    int c0 = blockIdx.y * 64;
    int b  = blockIdx.z;
    int tid = threadIdx.x;

#pragma unroll
    for (int r = 0; r < 4; ++r) {
        int f  = r * 256 + tid;
        int c  = f >> 4;
        int n4 = f & 15;
        float4 v = *(const float4*)(x + ((size_t)b * CH + c0 + c) * NPIX + n0 + n4 * 4);
        Tl[n4 * 4 + 0][c] = v.x;
        Tl[n4 * 4 + 1][c] = v.y;
        Tl[n4 * 4 + 2][c] = v.z;
        Tl[n4 * 4 + 3][c] = v.w;
    }
    __syncthreads();
#pragma unroll
    for (int r = 0; r < 2; ++r) {
        int f    = r * 256 + tid;
        int nrow = f >> 3;
        int c8   = f & 7;
        unsigned int pk[4];
#pragma unroll
        for (int p = 0; p < 4; ++p) {
            unsigned int lo = f2bf(Tl[nrow][c8 * 8 + p * 2 + 0]);
            unsigned int hi = f2bf(Tl[nrow][c8 * 8 + p * 2 + 1]);
            pk[p] = lo | (hi << 16);
        }
        *(uint4*)(xt + ((size_t)b * NPIX + n0 + nrow) * CH + c0 + c8 * 8) = *(uint4*)pk;
    }
}

// ---------------------------------------------------------------------------
// Kernel G: qkv GEMM. Stage 64n x 256c xt tile in LDS; loop 6 o-groups.
// og0 -> q[b][n][64], og1 -> k[b][n][64], og>=2 -> vp[b][o'][n].
// grid (64, 8), 256 threads.
// ---------------------------------------------------------------------------
__global__ void qkv_mfma(const unsigned short* __restrict__ xt,
                         const unsigned short* __restrict__ W_all,
                         const float* __restrict__ bias_all,
                         unsigned short* __restrict__ qg, unsigned short* __restrict__ kg,
                         unsigned short* __restrict__ vp) {
    __shared__ __align__(16) unsigned short Xl[64][264];

    int n0   = blockIdx.x * 64;
    int b    = blockIdx.y;
    int tid  = threadIdx.x;
    int lane = tid & 63;
    int w    = tid >> 6;
    int col  = lane & 15;
    int quad = lane >> 4;

#pragma unroll
    for (int r = 0; r < 8; ++r) {
        int f   = r * 256 + tid;
        int row = f >> 5;
        int c8  = f & 31;
        *(uint4*)&Xl[row][c8 * 8] = *(const uint4*)(xt + ((size_t)b * NPIX + n0 + row) * CH + c8 * 8);
    }
    __syncthreads();

#pragma unroll
    for (int og = 0; og < 6; ++og) {
        int o0 = og * 64;
        const unsigned short* Arow = W_all + (size_t)(o0 + w * 16 + col) * CH + quad * 8;

        f32x4 acc[4];
#pragma unroll
        for (int t = 0; t < 4; ++t) acc[t] = (f32x4){0.f, 0.f, 0.f, 0.f};

#pragma unroll
        for (int kc = 0; kc < 8; ++kc) {
            short8 a = *(const short8*)(Arow + kc * 32);
#pragma unroll
            for (int nt = 0; nt < 4; ++nt) {
                short8 bb = *(const short8*)&Xl[nt * 16 + col][kc * 32 + quad * 8];
                acc[nt] = MFMA16x16(a, bb, acc[nt]);
            }
        }

        float4 bias = *(const float4*)(bias_all + o0 + w * 16 + quad * 4);
        float bs[4] = {bias.x, bias.y, bias.z, bias.w};

        if (og < 2) {
            unsigned short* dst = (og == 0) ? qg : kg;
#pragma unroll
            for (int nt = 0; nt < 4; ++nt) {
                int n = n0 + nt * 16 + col;
                unsigned int pk[2];
#pragma unroll
                for (int p = 0; p < 2; ++p) {
                    unsigned int lo = f2bf(acc[nt][p * 2 + 0] + bs[p * 2 + 0]);
                    unsigned int hi = f2bf(acc[nt][p * 2 + 1] + bs[p * 2 + 1]);
                    pk[p] = lo | (hi << 16);
                }
                *(uint2*)(dst + ((size_t)b * NPIX + n) * 64 + w * 16 + quad * 4) = *(uint2*)pk;
            }
        } else {
#pragma unroll
            for (int nt = 0; nt < 4; ++nt) {
                int n = n0 + nt * 16 + col;
#pragma unroll
                for (int r = 0; r < 4; ++r) {
                    int oo = o0 - 128 + w * 16 + quad * 4 + r;
                    vp[((size_t)b * CH + oo) * NPIX + n] = f2bf(acc[nt][r] + bs[r]);
                }
            }
        }
    }
}

// ---------------------------------------------------------------------------
// Kernel A: attention v6. j-tile 64, i-window 64, 8 waves, ONE barrier/window.
// K iter-invariant in regs; V fragments global->reg (each V byte read once per
// block); Q + S through double-buffered LDS, S lags one window (B(t-1)
// overlaps A(t)). grid (64,8)=512 blocks. LDS 36.9 KB.
// ---------------------------------------------------------------------------
#define LQ 72
__global__ __launch_bounds__(512, 4)
void attn_v6(const unsigned short* __restrict__ qg,  // [B][N][64]
             const unsigned short* __restrict__ kg,  // [B][N][64]
             const unsigned short* __restrict__ vp,  // [B][256][N]
             const float* __restrict__ bg, float* __restrict__ out) {
    __shared__ __align__(16) unsigned short Qt[2][64][LQ];
    __shared__ __align__(16) unsigned short St[2][64][LQ];

    int j0   = blockIdx.x * 64;
    int b    = blockIdx.y;
    int tid  = threadIdx.x;
    int lane = tid & 63;
    int w    = tid >> 6;
    int col  = lane & 15;
    int quad = lane >> 4;

    int tiw = w >> 1;            // phase-A i-tile (split 4)
    int tjh = w & 1;             // phase-A j-tile half (split 2, 2 tj each)

    const size_t nb = (size_t)b * NPIX;
    int srow = tid >> 3, sq8 = tid & 7;     // staging coords (64 rows x 8 uint4)

    // iter-invariant K fragments (B-operand: n=j, k=ch)
    short8 bK[2][2];
#pragma unroll
    for (int tjl = 0; tjl < 2; ++tjl)
#pragma unroll
        for (int ks = 0; ks < 2; ++ks)
            bK[tjl][ks] = *(const short8*)(kg + (nb + j0 + (tjh * 2 + tjl) * 16 + col) * 64 + ks * 32 + quad * 8);

    // stage Qt[0] = Q(window 0)
    *(uint4*)&Qt[0][srow][sq8 * 8] = *(const uint4*)(qg + (nb + srow) * 64 + sq8 * 8);

    f32x4 acc[2][4];
#pragma unroll
    for (int ot = 0; ot < 2; ++ot)
#pragma unroll
        for (int tj = 0; tj < 4; ++tj) acc[ot][tj] = (f32x4){0.f, 0.f, 0.f, 0.f};

    __syncthreads();

    // ---- window 0: A(0) -> St[0]; stage Qt[1]; prefetch aV = V(0) ----
    uint4 qn = *(const uint4*)(qg + (nb + 64 + srow) * 64 + sq8 * 8);
    {
        short8 aq0 = *(const short8*)&Qt[0][tiw * 16 + col][quad * 8];
        short8 aq1 = *(const short8*)&Qt[0][tiw * 16 + col][32 + quad * 8];
#pragma unroll
        for (int tjl = 0; tjl < 2; ++tjl) {
            f32x4 s = (f32x4){0.f, 0.f, 0.f, 0.f};
            s = MFMA16x16(aq0, bK[tjl][0], s);
            s = MFMA16x16(aq1, bK[tjl][1], s);
            unsigned int pk[2];
#pragma unroll
            for (int p = 0; p < 2; ++p) {
                float e0 = s[p * 2 + 0], e1 = s[p * 2 + 1];
                e0 = (e0 > 0.f) ? e0 : (__expf(e0) - 1.f);
                e1 = (e1 > 0.f) ? e1 : (__expf(e1) - 1.f);
                e0 *= (1.f / (float)NPIX);
                e1 *= (1.f / (float)NPIX);
                pk[p] = (unsigned int)f2bf(e0) | ((unsigned int)f2bf(e1) << 16);
            }
            *(uint2*)&St[0][(tjh * 2 + tjl) * 16 + col][tiw * 16 + quad * 4] = *(uint2*)pk;
        }
    }
    *(uint4*)&Qt[1][srow][sq8 * 8] = qn;
    uint4 aV[2][2];
#pragma unroll
    for (int ot = 0; ot < 2; ++ot)
#pragma unroll
        for (int ks = 0; ks < 2; ++ks)
            aV[ot][ks] = *(const uint4*)(vp + ((size_t)b * CH + (2 * w + ot) * 16 + col) * NPIX + ks * 32 + quad * 8);
    __syncthreads();

    // ---- windows 1..63: A(t) || B(t-1) ----
    for (int t = 1; t < 64; ++t) {
        int i0 = t * 64;
        int p  = t & 1;
        uint4 q2 = *(const uint4*)(qg + (nb + (((t + 1) & 63) * 64) + srow) * 64 + sq8 * 8);

        // A(t): Qt[p] -> St[p]
        short8 aq0 = *(const short8*)&Qt[p][tiw * 16 + col][quad * 8];
        short8 aq1 = *(const short8*)&Qt[p][tiw * 16 + col][32 + quad * 8];
#pragma unroll
        for (int tjl = 0; tjl < 2; ++tjl) {
            f32x4 s = (f32x4){0.f, 0.f, 0.f, 0.f};
            s = MFMA16x16(aq0, bK[tjl][0], s);
            s = MFMA16x16(aq1, bK[tjl][1], s);
            unsigned int pk[2];
#pragma unroll
            for (int pp = 0; pp < 2; ++pp) {
                float e0 = s[pp * 2 + 0], e1 = s[pp * 2 + 1];
                e0 = (e0 > 0.f) ? e0 : (__expf(e0) - 1.f);
                e1 = (e1 > 0.f) ? e1 : (__expf(e1) - 1.f);
                e0 *= (1.f / (float)NPIX);
                e1 *= (1.f / (float)NPIX);
                pk[pp] = (unsigned int)f2bf(e0) | ((unsigned int)f2bf(e1) << 16);
            }
            *(uint2*)&St[p][(tjh * 2 + tjl) * 16 + col][tiw * 16 + quad * 4] = *(uint2*)pk;
        }
        // stage Qt[p^1] = Q(t+1)
        *(uint4*)&Qt[p ^ 1][srow][sq8 * 8] = q2;

        // B(t-1): St[p^1] x aV(=V(t-1))
#pragma unroll
        for (int ks = 0; ks < 2; ++ks) {
            short8 sb[4];
#pragma unroll
            for (int tj = 0; tj < 4; ++tj)
                sb[tj] = *(const short8*)&St[p ^ 1][tj * 16 + col][ks * 32 + quad * 8];
#pragma unroll
            for (int ot = 0; ot < 2; ++ot)
#pragma unroll
                for (int tj = 0; tj < 4; ++tj)
                    acc[ot][tj] = MFMA16x16(sb[tj], *(const short8*)&aV[ot][ks], acc[ot][tj]);
        }
        // reload aV = V(t)
#pragma unroll
        for (int ot = 0; ot < 2; ++ot)
#pragma unroll
            for (int ks = 0; ks < 2; ++ks)
                aV[ot][ks] = *(const uint4*)(vp + ((size_t)b * CH + (2 * w + ot) * 16 + col) * NPIX + i0 + ks * 32 + quad * 8);
        __syncthreads();
    }

    // ---- drain: B(63): St[1] x V(63) ----
#pragma unroll
    for (int ks = 0; ks < 2; ++ks) {
        short8 sb[4];
#pragma unroll
        for (int tj = 0; tj < 4; ++tj)
            sb[tj] = *(const short8*)&St[1][tj * 16 + col][ks * 32 + quad * 8];
#pragma unroll
        for (int ot = 0; ot < 2; ++ot)
#pragma unroll
            for (int tj = 0; tj < 4; ++tj)
                acc[ot][tj] = MFMA16x16(sb[tj], *(const short8*)&aV[ot][ks], acc[ot][tj]);
    }

    // epilogue: D col=o, rows=4 consecutive j -> float4 stores
#pragma unroll
    for (int ot = 0; ot < 2; ++ot) {
        int o = (w * 2 + ot) * 16 + col;
        float bgv = bg[o];
#pragma unroll
        for (int tj = 0; tj < 4; ++tj) {
            int j = j0 + tj * 16 + quad * 4;
            float4 st;
            st.x = acc[ot][tj][0] + bgv;
            st.y = acc[ot][tj][1] + bgv;
            st.z = acc[ot][tj][2] + bgv;
            st.w = acc[ot][tj][3] + bgv;
            *(float4*)&out[((size_t)b * CH + o) * NPIX + j] = st;
        }
    }
}

// ---------------------------------------------------------------------------
extern "C" void kernel_launch(void* const* d_in, const int* in_sizes, int n_in,
                              void* d_out, int out_size, void* d_ws, size_t ws_size,
                              hipStream_t stream) {
    const float* x  = (const float*)d_in[0];
    const float* wq = (const float*)d_in[1];
    const float* bq = (const float*)d_in[2];
    const float* wk = (const float*)d_in[3];
    const float* bk = (const float*)d_in[4];
    const float* wv = (const float*)d_in[5];
    const float* bv = (const float*)d_in[6];
    const float* wg = (const float*)d_in[7];
    const float* bg = (const float*)d_in[8];
    float* out = (float*)d_out;

    unsigned short* W_all = (unsigned short*)d_ws;
    float* bias_all = (float*)(W_all + 384 * 256);
    unsigned short* xt = (unsigned short*)(bias_all + 384);
    unsigned short* qg = xt + (size_t)BATCH * NPIX * CH;
    unsigned short* kg = qg + (size_t)BATCH * NPIX * 64;
    unsigned short* vp = kg + (size_t)BATCH * NPIX * 64;

    prep_kernel<<<dim3(48), dim3(256), 0, stream>>>(wq, bq, wk, bk, wv, bv, wg, W_all, bias_all);
    xpose_kernel<<<dim3(NPIX / 64, CH / 64, BATCH), dim3(256), 0, stream>>>(x, xt);
    qkv_mfma<<<dim3(NPIX / 64, BATCH), dim3(256), 0, stream>>>(xt, W_all, bias_all, qg, kg, vp);
    attn_v6<<<dim3(NPIX / 64, BATCH), dim3(512), 0, stream>>>(qg, kg, vp, bg, out);
}